// Round 5
// baseline (172.202 us; speedup 1.0000x reference)
//
#include <hip/hip_runtime.h>
#include <hip/hip_bf16.h>

// Problem constants
#define BPn   2048      // B*P
#define NEn   400
#define BT    8         // bp rows per tile
#define ET    8         // e rows per tile
#define TILE_R 64       // BT*ET
#define NT    12800     // (2048/8)*(400/8)
#define GRID  1024      // 4 blocks/CU * 256 CU

typedef __attribute__((ext_vector_type(8)))  short  short8;
typedef __attribute__((ext_vector_type(4)))  short  short4v;
typedef __attribute__((ext_vector_type(16))) float  f32x16;
typedef __attribute__((ext_vector_type(4)))  float  f32x4;

__device__ __forceinline__ unsigned short bf16c(float x) {
  return __builtin_bit_cast(unsigned short, __float2bfloat16(x));
}

// x * rcp(1+exp(-x)): avoids the IEEE div sequence.
__device__ __forceinline__ float silu_f(float x) {
  return x * __builtin_amdgcn_rcpf(1.0f + __expf(-x));
}

// ---------------- prep: hp[2048][128] and he[400][128] (f32) ----------------
__global__ void prep_emb(const int* __restrict__ z_j, const int* __restrict__ z_k,
                         const float* __restrict__ e_feat, const float* __restrict__ z_emb,
                         const float* __restrict__ W1, const float* __restrict__ b1,
                         float* __restrict__ hp, float* __restrict__ he)
{
  const int t = threadIdx.x;           // 0..127
  const int bidx = blockIdx.x;
  if (bidx < BPn) {
    const int zj = z_j[bidx], zk = z_k[bidx];
    const float* ej = z_emb + zj * 64;
    const float* ek = z_emb + zk * 64;
    float acc = b1[t];
    #pragma unroll 8
    for (int k = 0; k < 64; ++k) acc += ej[k] * W1[k * 128 + t];
    #pragma unroll 8
    for (int k = 0; k < 64; ++k) acc += ek[k] * W1[(64 + k) * 128 + t];
    hp[bidx * 128 + t] = acc;
  } else {
    const int e = bidx - BPn;          // 0..399
    float acc = 0.0f;
    #pragma unroll 8
    for (int k = 0; k < 32; ++k) acc += e_feat[e * 32 + k] * W1[(128 + k) * 128 + t];
    he[e * 128 + t] = acc;
  }
}

// ---------------- prep: weights to bf16 ----------------
// w2cm[n][k] = bf16(W2[k][n])  (col-major; read once per block into registers)
// w3f layout: [ks][lane][j] with B[k=ks*32+(lane>>4)*8+j][col=lane&15]
__global__ void prep_w(const float* __restrict__ W2, const float* __restrict__ W3,
                       unsigned short* __restrict__ w2cm, unsigned short* __restrict__ w3f)
{
  const int idx = blockIdx.x * 256 + threadIdx.x;
  if (idx < 16384) {
    const int n = idx >> 7, k = idx & 127;
    w2cm[idx] = bf16c(W2[k * 128 + n]);
  }
  if (idx < 2048) {
    const int ks = idx >> 9;
    const int l  = (idx >> 3) & 63;
    const int j  = idx & 7;
    const int k  = ks * 32 + ((l >> 4) & 3) * 8 + j;
    const int col = l & 15;
    w3f[idx] = bf16c(W3[k * 16 + col]);
  }
}

// ---------------- fused main: weights-stationary, 2D (bp,e) tiles ----------------
// Split A / H2 LDS buffers -> only 2 barriers per tile:
//   barrier#1: A writes complete -> GEMM1 reads A
//   barrier#2: H2 writes complete -> GEMM2 reads H2
// Safety of removed barriers: build(t+1) A-writes happen after barrier#2(t), by which
// point all waves finished GEMM1(t) A-reads; writeback(t+1) H-writes happen after
// barrier#1(t+1), by which point all waves finished GEMM2(t) H-reads.
__global__ __launch_bounds__(256, 4)
void fused_main(const float* __restrict__ hp, const float* __restrict__ he,
                const unsigned short* __restrict__ w2cm, const unsigned short* __restrict__ w3f,
                const float* __restrict__ b2, const float* __restrict__ b3,
                float* __restrict__ out)
{
  __shared__ __align__(16) unsigned short ldsA[8192]; // 16KB: A = bf16(silu(hp+he))
  __shared__ __align__(16) unsigned short ldsH[8192]; // 16KB: H2
  const int t    = threadIdx.x;
  const int lane = t & 63;
  const int wid  = t >> 6;
  const int wm = wid >> 1, wn = wid & 1;   // 2x2 wave grid; wave tile 32 rows x 64 cols
  const int c  = lane & 31, hi = lane >> 5;

  // ---- per-block hoists (tile-independent) ----
  short8 w2r[2][8];
  #pragma unroll
  for (int n = 0; n < 2; ++n) {
    const unsigned short* p = w2cm + (wn * 64 + n * 32 + c) * 128 + hi * 8;
    #pragma unroll
    for (int ks = 0; ks < 8; ++ks)
      w2r[n][ks] = *(const short8*)(p + ks * 16);
  }
  short8 w3r[4];
  #pragma unroll
  for (int ks = 0; ks < 4; ++ks)
    w3r[ks] = *(const short8*)(w3f + (ks * 64 + lane) * 8);

  const int l16 = lane & 15, l4 = lane >> 4;
  const float b3v = b3[l16];

  // build-A per-thread constants
  const int row0 = t >> 4;              // 0..15
  const int k8   = (t & 15) << 3;       // 0,8,...,120
  const int swzW = row0 << 4;           // (row&15)<<4 for all build rows
  const int ei0  = row0 & 7;            // e-index constant across i

  for (int tile = blockIdx.x; tile < NT; tile += GRID) {
    const int tbp = (int)(((unsigned)tile * 5243u) >> 18);  // tile/50 exact for tile<12800
    const int te  = tile - tbp * 50;
    const int b0  = tbp * BT;
    const int e0  = te * ET;

    // ---- build A = bf16(silu(hp[bp] + he[e])) into ldsA, swizzled ----
    {
      const float4* hev = (const float4*)(he + (e0 + ei0) * 128 + k8);
      const float4 g0 = hev[0], g1 = hev[1];   // he row: loop-invariant per thread
      #pragma unroll
      for (int i = 0; i < 4; ++i) {
        const int row = row0 + i * 16;         // 0..63
        const int bpi = row >> 3;
        const float4* hpv = (const float4*)(hp + (b0 + bpi) * 128 + k8);
        const float4 h0 = hpv[0], h1 = hpv[1];
        float v[8] = { h0.x + g0.x, h0.y + g0.y, h0.z + g0.z, h0.w + g0.w,
                       h1.x + g1.x, h1.y + g1.y, h1.z + g1.z, h1.w + g1.w };
        short8 av;
        #pragma unroll
        for (int j = 0; j < 8; ++j) av[j] = (short)bf16c(silu_f(v[j]));
        *(short8*)((char*)ldsA + ((row * 256 + k8 * 2) ^ swzW)) = av;
      }
    }
    __syncthreads();   // barrier#1: A ready

    // ---- GEMM1: acc[n] = H2pre^T fragments; B from registers ----
    f32x16 acc[2] = {};
    {
      const int rowA = wm * 32 + c;
      const int swzA = (c & 15) << 4;
      #pragma unroll
      for (int ks = 0; ks < 8; ++ks) {
        const int kb2 = (ks * 16 + hi * 8) * 2;
        short8 a0 = *(const short8*)((const char*)ldsA + ((rowA * 256 + kb2) ^ swzA));
        acc[0] = __builtin_amdgcn_mfma_f32_32x32x16_bf16(w2r[0][ks], a0, acc[0], 0, 0, 0);
        acc[1] = __builtin_amdgcn_mfma_f32_32x32x16_bf16(w2r[1][ks], a0, acc[1], 0, 0, 0);
      }
    }

    // ---- bias + silu -> H2 bf16 into ldsH; lane owns a row ----
    {
      const int swzH = (c & 15) << 4;
      char* rbase = (char*)ldsH + (wm * 32 + c) * 256;
      #pragma unroll
      for (int n = 0; n < 2; ++n) {
        #pragma unroll
        for (int q = 0; q < 4; ++q) {
          const int colb = wn * 64 + n * 32 + q * 8 + hi * 4;
          const float4 bv = *(const float4*)(b2 + colb);
          short4v pk;
          pk[0] = (short)bf16c(silu_f(acc[n][q * 4 + 0] + bv.x));
          pk[1] = (short)bf16c(silu_f(acc[n][q * 4 + 1] + bv.y));
          pk[2] = (short)bf16c(silu_f(acc[n][q * 4 + 2] + bv.z));
          pk[3] = (short)bf16c(silu_f(acc[n][q * 4 + 3] + bv.w));
          *(short4v*)(rbase + ((colb * 2) ^ swzH)) = pk;
        }
      }
    }
    __syncthreads();   // barrier#2: H2 ready

    // ---- GEMM2: H2 (64x128) @ W3 (128x16) ----
    f32x4 acc2 = {};
    {
      const int row2 = wid * 16 + l16;
      const int swz2 = l16 << 4;
      #pragma unroll
      for (int ks = 0; ks < 4; ++ks) {
        const int kb2 = ks * 64 + l4 * 16;
        short8 af = *(const short8*)((const char*)ldsH + ((row2 * 256 + kb2) ^ swz2));
        acc2 = __builtin_amdgcn_mfma_f32_16x16x32_bf16(af, w3r[ks], acc2, 0, 0, 0);
      }
    }

    // ---- store: tile row r -> global row (b0 + r>>3)*400 + (e0 + r&7) ----
    {
      const int obase = (b0 * 400 + e0);
      #pragma unroll
      for (int j = 0; j < 4; ++j) {
        const int r   = wid * 16 + l4 * 4 + j;
        const int rg  = obase + (r >> 3) * 400 + (r & 7);
        out[rg * 16 + l16] = acc2[j] + b3v;
      }
    }
    // no trailing barrier: next tile's barrier#1 provides the needed ordering
  }
}

extern "C" void kernel_launch(void* const* d_in, const int* in_sizes, int n_in,
                              void* d_out, int out_size, void* d_ws, size_t ws_size,
                              hipStream_t stream) {
  const int*   z_j    = (const int*)d_in[0];
  const int*   z_k    = (const int*)d_in[1];
  const float* e_feat = (const float*)d_in[2];
  const float* z_emb  = (const float*)d_in[3];
  const float* W1     = (const float*)d_in[4];
  const float* b1     = (const float*)d_in[5];
  const float* W2     = (const float*)d_in[6];
  const float* b2     = (const float*)d_in[7];
  const float* W3     = (const float*)d_in[8];
  const float* b3     = (const float*)d_in[9];
  float* out = (float*)d_out;
  char*  ws  = (char*)d_ws;

  float*          hp   = (float*)(ws);                     // 2048*128*4 = 1 MB
  float*          he   = (float*)(ws + (1 << 20));         // 400*128*4  = 200 KB
  unsigned short* w2cm = (unsigned short*)(ws + 0x140000); // 32 KB
  unsigned short* w3f  = (unsigned short*)(ws + 0x148000); // 4 KB

  hipLaunchKernelGGL(prep_emb, dim3(BPn + NEn), dim3(128), 0, stream,
                     z_j, z_k, e_feat, z_emb, W1, b1, hp, he);
  hipLaunchKernelGGL(prep_w, dim3(64), dim3(256), 0, stream, W2, W3, w2cm, w3f);
  hipLaunchKernelGGL(fused_main, dim3(GRID), dim3(256), 0, stream,
                     hp, he, w2cm, w3f, b2, b3, out);
}

// Round 6
// 95.446 us; speedup vs baseline: 1.8042x; 1.8042x over previous
//
#include <hip/hip_runtime.h>
#include <hip/hip_bf16.h>

// Problem constants
#define BPn   2048      // B*P
#define NEn   400
#define BT    8         // bp rows per tile
#define ET    8         // e rows per tile
#define NT    12800     // (2048/8)*(400/8)
#define GRID  768       // 3 blocks/CU * 256 CU (register budget 170/wave -> w2r stays resident)

typedef __attribute__((ext_vector_type(8)))  short  short8;
typedef __attribute__((ext_vector_type(4)))  short  short4v;
typedef __attribute__((ext_vector_type(16))) float  f32x16;
typedef __attribute__((ext_vector_type(4)))  float  f32x4;

__device__ __forceinline__ unsigned short bf16c(float x) {
  return __builtin_bit_cast(unsigned short, __float2bfloat16(x));
}

// x * rcp(1+exp(-x)): avoids the IEEE div sequence.
__device__ __forceinline__ float silu_f(float x) {
  return x * __builtin_amdgcn_rcpf(1.0f + __expf(-x));
}

// async global->LDS, 16B per lane. LDS dest is wave-uniform base + lane*16.
__device__ __forceinline__ void glds16(const void* g, void* l) {
  __builtin_amdgcn_global_load_lds(
      (const __attribute__((address_space(1))) unsigned int*)g,
      (__attribute__((address_space(3))) unsigned int*)l, 16, 0, 0);
}

// ---------------- prep: hp[2048][128] and he[400][128] (f32) ----------------
__global__ void prep_emb(const int* __restrict__ z_j, const int* __restrict__ z_k,
                         const float* __restrict__ e_feat, const float* __restrict__ z_emb,
                         const float* __restrict__ W1, const float* __restrict__ b1,
                         float* __restrict__ hp, float* __restrict__ he)
{
  const int t = threadIdx.x;           // 0..127
  const int bidx = blockIdx.x;
  if (bidx < BPn) {
    const int zj = z_j[bidx], zk = z_k[bidx];
    const float* ej = z_emb + zj * 64;
    const float* ek = z_emb + zk * 64;
    float acc = b1[t];
    #pragma unroll 8
    for (int k = 0; k < 64; ++k) acc += ej[k] * W1[k * 128 + t];
    #pragma unroll 8
    for (int k = 0; k < 64; ++k) acc += ek[k] * W1[(64 + k) * 128 + t];
    hp[bidx * 128 + t] = acc;
  } else {
    const int e = bidx - BPn;          // 0..399
    float acc = 0.0f;
    #pragma unroll 8
    for (int k = 0; k < 32; ++k) acc += e_feat[e * 32 + k] * W1[(128 + k) * 128 + t];
    he[e * 128 + t] = acc;
  }
}

// ---------------- prep: weights to bf16 ----------------
// w2cm[n][k] = bf16(W2[k][n])  (col-major; read once per block into registers)
// w3f layout: [ks][lane][j] with B[k=ks*32+(lane>>4)*8+j][col=lane&15]
__global__ void prep_w(const float* __restrict__ W2, const float* __restrict__ W3,
                       unsigned short* __restrict__ w2cm, unsigned short* __restrict__ w3f)
{
  const int idx = blockIdx.x * 256 + threadIdx.x;
  if (idx < 16384) {
    const int n = idx >> 7, k = idx & 127;
    w2cm[idx] = bf16c(W2[k * 128 + n]);
  }
  if (idx < 2048) {
    const int ks = idx >> 9;
    const int l  = (idx >> 3) & 63;
    const int j  = idx & 7;
    const int k  = ks * 32 + ((l >> 4) & 3) * 8 + j;
    const int col = l & 15;
    w3f[idx] = bf16c(W3[k * 16 + col]);
  }
}

// ---------------- fused main ----------------
// Per-tile phase order (2 barriers):
//   STAGE(t+1)[glds] -> GEMM1(t) -> siluWB(t)->ldsH -> bar2 -> GEMM2(t) + BUILD(t+1) -> stores(t) -> bar1
// bar2's implicit vmcnt(0)+barrier makes the staged S(t+1) visible to all waves.
// ldsA overwrite in BUILD(t+1) is safe: all GEMM1(t) A-reads completed before bar2.
// ldsS overwrite by STAGE(t+2) is safe: all BUILD(t+1) S-reads completed before bar1.
__global__ __launch_bounds__(256, 3)
void fused_main(const float* __restrict__ hp, const float* __restrict__ he,
                const unsigned short* __restrict__ w2cm, const unsigned short* __restrict__ w3f,
                const float* __restrict__ b2, const float* __restrict__ b3,
                float* __restrict__ out)
{
  __shared__ __align__(16) unsigned short ldsA[8192]; // 16KB: A = bf16(silu(hp+he))
  __shared__ __align__(16) unsigned short ldsH[8192]; // 16KB: H2
  __shared__ __align__(16) float          ldsS[2048]; // 8KB staging: [0:1024) hp rows, [1024:2048) he rows
  const int t    = threadIdx.x;
  const int lane = t & 63;
  const int wid  = t >> 6;
  const int wm = wid >> 1, wn = wid & 1;   // 2x2 wave grid; wave tile 32 rows x 64 cols
  const int c  = lane & 31, hi = lane >> 5;

  // ---- per-block hoists (tile-independent) ----
  short8 w2r[2][8];
  #pragma unroll
  for (int n = 0; n < 2; ++n) {
    const unsigned short* p = w2cm + (wn * 64 + n * 32 + c) * 128 + hi * 8;
    #pragma unroll
    for (int ks = 0; ks < 8; ++ks)
      w2r[n][ks] = *(const short8*)(p + ks * 16);
  }
  short8 w3r[4];
  #pragma unroll
  for (int ks = 0; ks < 4; ++ks)
    w3r[ks] = *(const short8*)(w3f + (ks * 64 + lane) * 8);

  const int l16 = lane & 15, l4 = lane >> 4;
  const float b3v = b3[l16];

  // build-A per-thread constants
  const int row0 = t >> 4;              // 0..15
  const int kb   = (t & 15) << 5;       // byte offset within a 512B f32 row: (t&15)*32
  const int k16  = (t & 15) << 4;       // byte offset within a 256B bf16 row
  const int swzW = row0 << 4;           // (row&15)<<4 for all build rows
  const int ei0  = row0 & 7;            // e-index constant across i

  // STAGE: issue 2 glds per wave for tile (b0,e0): hp rows b0..b0+7, he rows e0..e0+7
  #define STAGE(b0_, e0_) do { \
    glds16(hp + (b0_) * 128 + wid * 256 + lane * 4, (char*)ldsS + wid * 1024); \
    glds16(he + (e0_) * 128 + wid * 256 + lane * 4, (char*)ldsS + 4096 + wid * 1024); \
  } while (0)

  // BUILD: ldsS -> silu -> bf16 A tile in ldsA (swizzled)
  #define BUILD() do { \
    const char* heb = (const char*)ldsS + 4096 + ei0 * 512 + kb; \
    const float4 g0 = *(const float4*)heb, g1 = *((const float4*)heb + 1); \
    _Pragma("unroll") \
    for (int i = 0; i < 4; ++i) { \
      const int row = row0 + i * 16; \
      const char* hb = (const char*)ldsS + (row >> 3) * 512 + kb; \
      const float4 h0 = *(const float4*)hb, h1 = *((const float4*)hb + 1); \
      float v[8] = { h0.x + g0.x, h0.y + g0.y, h0.z + g0.z, h0.w + g0.w, \
                     h1.x + g1.x, h1.y + g1.y, h1.z + g1.z, h1.w + g1.w }; \
      short8 av; \
      _Pragma("unroll") \
      for (int j = 0; j < 8; ++j) av[j] = (short)bf16c(silu_f(v[j])); \
      *(short8*)((char*)ldsA + ((row * 256 + k16) ^ swzW)) = av; \
    } \
  } while (0)

  // ---- prologue: stage + build tile0 ----
  {
    const int tile0 = blockIdx.x;
    const int tbp = (int)(((unsigned)tile0 * 5243u) >> 18);  // tile/50 exact for tile<12800
    const int te  = tile0 - tbp * 50;
    STAGE(tbp * BT, te * ET);
  }
  __syncthreads();   // staged S(tile0) visible to all waves
  BUILD();
  __syncthreads();   // barrier#1: A(tile0) ready; ldsS free

  for (int tile = blockIdx.x; tile < NT; tile += GRID) {
    const int tbp = (int)(((unsigned)tile * 5243u) >> 18);
    const int te  = tile - tbp * 50;
    const int b0  = tbp * BT;
    const int e0  = te * ET;

    const int nxt = tile + GRID;
    const bool have_next = (nxt < NT);
    if (have_next) {
      const int ntbp = (int)(((unsigned)nxt * 5243u) >> 18);
      const int nte  = nxt - ntbp * 50;
      STAGE(ntbp * BT, nte * ET);   // in flight until bar2
    }

    // ---- GEMM1: acc[n] = H2pre^T fragments; B from registers ----
    f32x16 acc[2] = {};
    {
      const int rowA = wm * 32 + c;
      const int swzA = (c & 15) << 4;
      #pragma unroll
      for (int ks = 0; ks < 8; ++ks) {
        const int kb2 = (ks * 16 + hi * 8) * 2;
        short8 a0 = *(const short8*)((const char*)ldsA + ((rowA * 256 + kb2) ^ swzA));
        acc[0] = __builtin_amdgcn_mfma_f32_32x32x16_bf16(w2r[0][ks], a0, acc[0], 0, 0, 0);
        acc[1] = __builtin_amdgcn_mfma_f32_32x32x16_bf16(w2r[1][ks], a0, acc[1], 0, 0, 0);
      }
    }

    // ---- bias + silu -> H2 bf16 into ldsH; lane owns a row ----
    {
      const int swzH = (c & 15) << 4;
      char* rbase = (char*)ldsH + (wm * 32 + c) * 256;
      #pragma unroll
      for (int n = 0; n < 2; ++n) {
        #pragma unroll
        for (int q = 0; q < 4; ++q) {
          const int colb = wn * 64 + n * 32 + q * 8 + hi * 4;
          const float4 bv = *(const float4*)(b2 + colb);
          short4v pk;
          pk[0] = (short)bf16c(silu_f(acc[n][q * 4 + 0] + bv.x));
          pk[1] = (short)bf16c(silu_f(acc[n][q * 4 + 1] + bv.y));
          pk[2] = (short)bf16c(silu_f(acc[n][q * 4 + 2] + bv.z));
          pk[3] = (short)bf16c(silu_f(acc[n][q * 4 + 3] + bv.w));
          *(short4v*)(rbase + ((colb * 2) ^ swzH)) = pk;
        }
      }
    }
    __syncthreads();   // barrier#2: H2 ready; S(t+1) visible; ldsA free

    // ---- GEMM2: H2 (64x128) @ W3 (128x16) ----
    f32x4 acc2 = {};
    {
      const int row2 = wid * 16 + l16;
      const int swz2 = l16 << 4;
      #pragma unroll
      for (int ks = 0; ks < 4; ++ks) {
        const int kb2 = ks * 64 + l4 * 16;
        short8 af = *(const short8*)((const char*)ldsH + ((row2 * 256 + kb2) ^ swz2));
        acc2 = __builtin_amdgcn_mfma_f32_16x16x32_bf16(af, w3r[ks], acc2, 0, 0, 0);
      }
    }

    // ---- build A(t+1) from staged S(t+1) (interleaves with GEMM2 latency) ----
    if (have_next) BUILD();

    // ---- store: tile row r -> global row (b0 + r>>3)*400 + (e0 + r&7) ----
    {
      const int obase = (b0 * 400 + e0);
      #pragma unroll
      for (int j = 0; j < 4; ++j) {
        const int r   = wid * 16 + l4 * 4 + j;
        const int rg  = obase + (r >> 3) * 400 + (r & 7);
        out[rg * 16 + l16] = acc2[j] + b3v;
      }
    }
    __syncthreads();   // barrier#1: A(t+1) ready; ldsS free; ldsH free
  }
  #undef STAGE
  #undef BUILD
}

extern "C" void kernel_launch(void* const* d_in, const int* in_sizes, int n_in,
                              void* d_out, int out_size, void* d_ws, size_t ws_size,
                              hipStream_t stream) {
  const int*   z_j    = (const int*)d_in[0];
  const int*   z_k    = (const int*)d_in[1];
  const float* e_feat = (const float*)d_in[2];
  const float* z_emb  = (const float*)d_in[3];
  const float* W1     = (const float*)d_in[4];
  const float* b1     = (const float*)d_in[5];
  const float* W2     = (const float*)d_in[6];
  const float* b2     = (const float*)d_in[7];
  const float* W3     = (const float*)d_in[8];
  const float* b3     = (const float*)d_in[9];
  float* out = (float*)d_out;
  char*  ws  = (char*)d_ws;

  float*          hp   = (float*)(ws);                     // 2048*128*4 = 1 MB
  float*          he   = (float*)(ws + (1 << 20));         // 400*128*4  = 200 KB
  unsigned short* w2cm = (unsigned short*)(ws + 0x140000); // 32 KB
  unsigned short* w3f  = (unsigned short*)(ws + 0x148000); // 4 KB

  hipLaunchKernelGGL(prep_emb, dim3(BPn + NEn), dim3(128), 0, stream,
                     z_j, z_k, e_feat, z_emb, W1, b1, hp, he);
  hipLaunchKernelGGL(prep_w, dim3(64), dim3(256), 0, stream, W2, W3, w2cm, w3f);
  hipLaunchKernelGGL(fused_main, dim3(GRID), dim3(256), 0, stream,
                     hp, he, w2cm, w3f, b2, b3, out);
}

// Round 7
// 87.058 us; speedup vs baseline: 1.9780x; 1.0963x over previous
//
#include <hip/hip_runtime.h>
#include <hip/hip_bf16.h>

// Problem constants
#define BPn   2048      // B*P
#define NEn   400
#define BT    4         // bp rows per tile
#define ET    8         // e rows per tile  -> 32-row tiles
#define NT    25600     // (2048/4)*(400/8)
#define GRID  1536      // 6 blocks/CU * 256 CU (2-wave blocks -> phase diversity)

typedef __attribute__((ext_vector_type(8)))  short  short8;
typedef __attribute__((ext_vector_type(4)))  short  short4v;
typedef __attribute__((ext_vector_type(16))) float  f32x16;
typedef __attribute__((ext_vector_type(4)))  float  f32x4;

__device__ __forceinline__ unsigned short bf16c(float x) {
  return __builtin_bit_cast(unsigned short, __float2bfloat16(x));
}

// x * rcp(1+exp(-x)): avoids the IEEE div sequence.
__device__ __forceinline__ float silu_f(float x) {
  return x * __builtin_amdgcn_rcpf(1.0f + __expf(-x));
}

// async global->LDS, 16B per lane. LDS dest is wave-uniform base + lane*16.
__device__ __forceinline__ void glds16(const void* g, void* l) {
  __builtin_amdgcn_global_load_lds(
      (const __attribute__((address_space(1))) unsigned int*)g,
      (__attribute__((address_space(3))) unsigned int*)l, 16, 0, 0);
}

// ---------------- prep: hp[2048][128] and he[400][128] (f32) ----------------
__global__ void prep_emb(const int* __restrict__ z_j, const int* __restrict__ z_k,
                         const float* __restrict__ e_feat, const float* __restrict__ z_emb,
                         const float* __restrict__ W1, const float* __restrict__ b1,
                         float* __restrict__ hp, float* __restrict__ he)
{
  const int t = threadIdx.x;           // 0..127
  const int bidx = blockIdx.x;
  if (bidx < BPn) {
    const int zj = z_j[bidx], zk = z_k[bidx];
    const float* ej = z_emb + zj * 64;
    const float* ek = z_emb + zk * 64;
    float acc = b1[t];
    #pragma unroll 8
    for (int k = 0; k < 64; ++k) acc += ej[k] * W1[k * 128 + t];
    #pragma unroll 8
    for (int k = 0; k < 64; ++k) acc += ek[k] * W1[(64 + k) * 128 + t];
    hp[bidx * 128 + t] = acc;
  } else {
    const int e = bidx - BPn;          // 0..399
    float acc = 0.0f;
    #pragma unroll 8
    for (int k = 0; k < 32; ++k) acc += e_feat[e * 32 + k] * W1[(128 + k) * 128 + t];
    he[e * 128 + t] = acc;
  }
}

// ---------------- prep: weights to bf16 ----------------
// w2cm[n][k] = bf16(W2[k][n])  (col-major; read once per block into registers)
// w3f layout: [ks][lane][j] with B[k=ks*32+(lane>>4)*8+j][col=lane&15]
__global__ void prep_w(const float* __restrict__ W2, const float* __restrict__ W3,
                       unsigned short* __restrict__ w2cm, unsigned short* __restrict__ w3f)
{
  const int idx = blockIdx.x * 256 + threadIdx.x;
  if (idx < 16384) {
    const int n = idx >> 7, k = idx & 127;
    w2cm[idx] = bf16c(W2[k * 128 + n]);
  }
  if (idx < 2048) {
    const int ks = idx >> 9;
    const int l  = (idx >> 3) & 63;
    const int j  = idx & 7;
    const int k  = ks * 32 + ((l >> 4) & 3) * 8 + j;
    const int col = l & 15;
    w3f[idx] = bf16c(W3[k * 16 + col]);
  }
}

// ---------------- fused main: 2-wave blocks, 32-row tiles ----------------
// Per-tile phase order (2 barriers):
//   STAGE(t+1)[glds] -> GEMM1(t) -> siluWB(t)->ldsH -> bar2 -> GEMM2(t) + BUILD(t+1) -> stores(t) -> bar1
// bar2's implicit vmcnt(0)+barrier makes staged S(t+1) visible to both waves.
// ldsA overwrite in BUILD(t+1) safe: GEMM1(t) A-reads done before bar2.
// ldsS overwrite by STAGE(t+2) safe: BUILD(t+1) S-reads done before bar1.
__global__ __launch_bounds__(128, 3)
void fused_main(const float* __restrict__ hp, const float* __restrict__ he,
                const unsigned short* __restrict__ w2cm, const unsigned short* __restrict__ w3f,
                const float* __restrict__ b2, const float* __restrict__ b3,
                float* __restrict__ out)
{
  __shared__ __align__(16) unsigned short ldsA[4096]; // 8KB: A = bf16(silu(hp+he)), 32 rows
  __shared__ __align__(16) unsigned short ldsH[4096]; // 8KB: H2, 32 rows
  __shared__ __align__(16) float          ldsS[1536]; // 6KB staging: [0,2KB) hp 4 rows, [2KB,6KB) he 8 rows
  __shared__ __align__(16) float          ldsB2[128]; // 512B: b2
  const int t    = threadIdx.x;       // 0..127
  const int lane = t & 63;
  const int wid  = t >> 6;            // 0..1; wave owns 64 output cols
  const int c  = lane & 31, hi = lane >> 5;

  // ---- per-block hoists (tile-independent) ----
  short8 w2r[2][8];
  #pragma unroll
  for (int n = 0; n < 2; ++n) {
    const unsigned short* p = w2cm + (wid * 64 + n * 32 + c) * 128 + hi * 8;
    #pragma unroll
    for (int ks = 0; ks < 8; ++ks)
      w2r[n][ks] = *(const short8*)(p + ks * 16);
  }
  short8 w3r[4];
  #pragma unroll
  for (int ks = 0; ks < 4; ++ks)
    w3r[ks] = *(const short8*)(w3f + (ks * 64 + lane) * 8);

  const int l16 = lane & 15, l4 = lane >> 4;
  const float b3v = b3[l16];
  ldsB2[t] = b2[t];

  // build-A per-thread constants: tile row = bp_local*8 + e_local
  const int row0 = t >> 4;              // 0..7  = e_local (fixed per thread)
  const int kb   = (t & 15) << 5;       // byte offset within a 512B f32 row
  const int k16  = (t & 15) << 4;       // byte offset within a 256B bf16 row

  // STAGE: 3 glds16 per wave. segs 0-1: hp rows b0..b0+3; segs 2-5: he rows e0..e0+7
  #define STAGE(b0_, e0_) do { \
    _Pragma("unroll") \
    for (int s_ = 0; s_ < 3; ++s_) { \
      const int seg_ = wid * 3 + s_; \
      const float* src_ = (seg_ < 2) ? (hp + (b0_) * 128 + seg_ * 256 + lane * 4) \
                                     : (he + (e0_) * 128 + (seg_ - 2) * 256 + lane * 4); \
      glds16(src_, (char*)ldsS + seg_ * 1024); \
    } \
  } while (0)

  // BUILD: ldsS -> silu -> bf16 A tile in ldsA (swizzled)
  #define BUILD() do { \
    const char* heb = (const char*)ldsS + 2048 + row0 * 512 + kb; \
    const float4 g0 = *(const float4*)heb, g1 = *((const float4*)heb + 1); \
    _Pragma("unroll") \
    for (int i = 0; i < 4; ++i) { \
      const int row = i * 8 + row0; \
      const char* hb = (const char*)ldsS + i * 512 + kb; \
      const float4 h0 = *(const float4*)hb, h1 = *((const float4*)hb + 1); \
      float v[8] = { h0.x + g0.x, h0.y + g0.y, h0.z + g0.z, h0.w + g0.w, \
                     h1.x + g1.x, h1.y + g1.y, h1.z + g1.z, h1.w + g1.w }; \
      short8 av; \
      _Pragma("unroll") \
      for (int j = 0; j < 8; ++j) av[j] = (short)bf16c(silu_f(v[j])); \
      *(short8*)((char*)ldsA + ((row * 256 + k16) ^ ((row & 15) << 4))) = av; \
    } \
  } while (0)

  // ---- prologue: stage + build tile0 ----
  {
    const int tile0 = blockIdx.x;
    const int tbp = (int)(((unsigned)tile0 * 5243u) >> 18);  // tile/50 exact for tile<25600
    const int te  = tile0 - tbp * 50;
    STAGE(tbp * BT, te * ET);
  }
  __syncthreads();   // S(tile0) + ldsB2 visible
  BUILD();
  __syncthreads();   // bar#1: A(tile0) ready; ldsS free

  for (int tile = blockIdx.x; tile < NT; tile += GRID) {
    const int tbp = (int)(((unsigned)tile * 5243u) >> 18);
    const int te  = tile - tbp * 50;
    const int b0  = tbp * BT;
    const int e0  = te * ET;

    const int nxt = tile + GRID;
    const bool have_next = (nxt < NT);
    if (have_next) {
      const int ntbp = (int)(((unsigned)nxt * 5243u) >> 18);
      const int nte  = nxt - ntbp * 50;
      STAGE(ntbp * BT, nte * ET);   // in flight until bar2
    }

    // ---- GEMM1: acc[n] = H2pre^T fragments; B from registers ----
    f32x16 acc[2] = {};
    {
      const int swzA = (c & 15) << 4;
      #pragma unroll
      for (int ks = 0; ks < 8; ++ks) {
        const int kb2 = (ks * 16 + hi * 8) * 2;
        short8 a0 = *(const short8*)((const char*)ldsA + ((c * 256 + kb2) ^ swzA));
        acc[0] = __builtin_amdgcn_mfma_f32_32x32x16_bf16(w2r[0][ks], a0, acc[0], 0, 0, 0);
        acc[1] = __builtin_amdgcn_mfma_f32_32x32x16_bf16(w2r[1][ks], a0, acc[1], 0, 0, 0);
      }
    }

    // ---- bias + silu -> H2 bf16 into ldsH; lane owns row c ----
    {
      const int swzH = (c & 15) << 4;
      char* rbase = (char*)ldsH + c * 256;
      #pragma unroll
      for (int n = 0; n < 2; ++n) {
        #pragma unroll
        for (int q = 0; q < 4; ++q) {
          const int colb = wid * 64 + n * 32 + q * 8 + hi * 4;
          const float4 bv = *(const float4*)(ldsB2 + colb);
          short4v pk;
          pk[0] = (short)bf16c(silu_f(acc[n][q * 4 + 0] + bv.x));
          pk[1] = (short)bf16c(silu_f(acc[n][q * 4 + 1] + bv.y));
          pk[2] = (short)bf16c(silu_f(acc[n][q * 4 + 2] + bv.z));
          pk[3] = (short)bf16c(silu_f(acc[n][q * 4 + 3] + bv.w));
          *(short4v*)(rbase + ((colb * 2) ^ swzH)) = pk;
        }
      }
    }
    __syncthreads();   // bar#2: H2 ready; S(t+1) visible; ldsA free

    // ---- GEMM2: H2 (32x128) @ W3 (128x16) ----
    f32x4 acc2 = {};
    {
      const int row2 = wid * 16 + l16;
      const int swz2 = l16 << 4;
      #pragma unroll
      for (int ks = 0; ks < 4; ++ks) {
        const int kb2 = ks * 64 + l4 * 16;
        short8 af = *(const short8*)((const char*)ldsH + ((row2 * 256 + kb2) ^ swz2));
        acc2 = __builtin_amdgcn_mfma_f32_16x16x32_bf16(af, w3r[ks], acc2, 0, 0, 0);
      }
    }

    // ---- build A(t+1) from staged S(t+1) (overlaps GEMM2 latency) ----
    if (have_next) BUILD();

    // ---- store: tile row r -> global row (b0 + r>>3)*400 + (e0 + r&7) ----
    {
      const int obase = (b0 * 400 + e0);
      #pragma unroll
      for (int j = 0; j < 4; ++j) {
        const int r   = wid * 16 + l4 * 4 + j;
        const int rg  = obase + (r >> 3) * 400 + (r & 7);
        out[rg * 16 + l16] = acc2[j] + b3v;
      }
    }
    __syncthreads();   // bar#1: A(t+1) ready; ldsS free; ldsH free
  }
  #undef STAGE
  #undef BUILD
}

extern "C" void kernel_launch(void* const* d_in, const int* in_sizes, int n_in,
                              void* d_out, int out_size, void* d_ws, size_t ws_size,
                              hipStream_t stream) {
  const int*   z_j    = (const int*)d_in[0];
  const int*   z_k    = (const int*)d_in[1];
  const float* e_feat = (const float*)d_in[2];
  const float* z_emb  = (const float*)d_in[3];
  const float* W1     = (const float*)d_in[4];
  const float* b1     = (const float*)d_in[5];
  const float* W2     = (const float*)d_in[6];
  const float* b2     = (const float*)d_in[7];
  const float* W3     = (const float*)d_in[8];
  const float* b3     = (const float*)d_in[9];
  float* out = (float*)d_out;
  char*  ws  = (char*)d_ws;

  float*          hp   = (float*)(ws);                     // 2048*128*4 = 1 MB
  float*          he   = (float*)(ws + (1 << 20));         // 400*128*4  = 200 KB
  unsigned short* w2cm = (unsigned short*)(ws + 0x140000); // 32 KB
  unsigned short* w3f  = (unsigned short*)(ws + 0x148000); // 4 KB

  hipLaunchKernelGGL(prep_emb, dim3(BPn + NEn), dim3(128), 0, stream,
                     z_j, z_k, e_feat, z_emb, W1, b1, hp, he);
  hipLaunchKernelGGL(prep_w, dim3(64), dim3(256), 0, stream, W2, W3, w2cm, w3f);
  hipLaunchKernelGGL(fused_main, dim3(GRID), dim3(128), 0, stream,
                     hp, he, w2cm, w3f, b2, b3, out);
}